// Round 1
// 475.404 us; speedup vs baseline: 1.0031x; 1.0031x over previous
//
#include <hip/hip_runtime.h>

// TrendGRU R8: kill the per-timestep LDS h-roundtrip. The h redistribution
// between wave halves (lane e <-> lane e+32) is done with v_permlane32_swap
// on the packed-bf16 dwords P0..P5 instead of 3x ds_write_b64 + 2x
// ds_read_b128 + lgkmcnt (which cost ~120cy unhidden latency + 6.3M bank
// conflict cycles at 1 wave/SIMD). bf16 packing now uses v_cvt_pk_bf16_f32
// (RNE, bit-identical to the old manual round) - 1 instr per pair instead
// of 7. r/z sigmoids share one v_rcp via rcp(dr*dz).
// Mapping check (swap(Pa,Pb) -> {dst.lo|src.loToHi , dst.hiToLo|src.hi}):
//   P0=[0,1|4,5] P2=[8,9|12,13]: swap(P0,P2).x = B0.w0 ([0,1]lo,[8,9]hi),
//   .y = B0.w2 ([4,5]lo,[12,13]hi); swap(P1,P3) likewise w1/w3.
//   B1 low lanes: w0=P4 w1=P5 w2=swap(P4,P4).y w3=swap(P5,P5).y; high lanes
//   overwritten by the k24..31 x-pack as before.
// Everything else (A fragments, hi/lo W split, K-stream, FC head) unchanged.

#define GRU_T 512
#define FS 28   // FC LDS row stride in floats (16B-aligned float4 rows)

typedef __attribute__((ext_vector_type(8)))  short bf16x8;
typedef __attribute__((ext_vector_type(16))) float f32x16;
typedef __attribute__((ext_vector_type(2)))  unsigned uint2v;

__device__ __forceinline__ float bf16hi_f(float v) {   // RNE-to-bf16, as float
    unsigned u = __float_as_uint(v);
    u = (u + 0x7FFFu + ((u >> 16) & 1u)) & 0xFFFF0000u;
    return __uint_as_float(u);
}
__device__ __forceinline__ unsigned bf16_rne(float v) {
    unsigned u = __float_as_uint(v);
    return (u + 0x7FFFu + ((u >> 16) & 1u)) >> 16;
}
// packed RNE f32->bf16: dst = [bf16(lo) | bf16(hi)<<16]
__device__ __forceinline__ unsigned cvt_pk_bf16(float lo, float hi) {
    unsigned r;
    asm("v_cvt_pk_bf16_f32 %0, %1, %2" : "=v"(r) : "v"(lo), "v"(hi));
    return r;
}
// v pre-scaled by 2*log2(e): tanh = 1 - 2/(2^v+1)
__device__ __forceinline__ float tnhf(float v) {
    return fmaf(-2.0f, __builtin_amdgcn_rcpf(1.0f + __builtin_amdgcn_exp2f(v)), 1.0f);
}
__device__ __forceinline__ f32x16 mfma32(bf16x8 a, bf16x8 b, f32x16 c) {
    return __builtin_amdgcn_mfma_f32_32x32x16_bf16(a, b, c, 0, 0, 0);
}

__global__ __launch_bounds__(64) void trend_gru_mfma32(
    const float* __restrict__ x,     // (B, T)
    const float* __restrict__ W_ih,  // (72,)
    const float* __restrict__ b_ih,  // (72,)
    const float* __restrict__ W_hh,  // (72, 24) rows r,z,n
    const float* __restrict__ b_hh,  // (72,)
    const float* __restrict__ fc_w,  // (2, 24)
    const float* __restrict__ fc_b,  // (2,)
    float* __restrict__ out)         // (B, 2)
{
    const int lane = threadIdx.x;
    const int e    = lane & 31;          // element (B-col / C-col)
    const int half = lane >> 5;
    const int elem0 = blockIdx.x * 32;

    __shared__ __align__(16) float Flds[32 * FS];

    const float L2E = 1.4426950408889634f;

    // ---- A fragments (weights), built once: A[gate][kstep][hi/lo] ----
    // A layout: row m = lane&31, k = kstep*16 + (lane>>5)*8 + jj.
    bf16x8 A[3][2][2];
#pragma unroll
    for (int g = 0; g < 3; ++g) {
        const float sc = (g == 2) ? 2.0f * L2E : L2E;
        const int m = e;
        const bool valid = m < 24;
        const int R = g * 24 + (valid ? m : 0);
        const float wx = (g < 2 && valid) ? sc * W_ih[R] : 0.0f;
        const float bb = valid ? sc * ((g < 2) ? (b_ih[R] + b_hh[R]) : b_hh[R]) : 0.0f;
        const float wxh = bf16hi_f(wx), bbh = bf16hi_f(bb);
#pragma unroll
        for (int s = 0; s < 2; ++s) {
            bf16x8 fh, fl;
#pragma unroll
            for (int jj = 0; jj < 8; ++jj) {
                const int k = s * 16 + half * 8 + jj;
                float vh = 0.0f, vl = 0.0f;
                if (valid && k < 24) {
                    const float w  = sc * W_hh[R * 24 + k];
                    const float wh = bf16hi_f(w);
                    vh = wh; vl = w - wh;
                } else if (valid) {
                    if (k == 24 || k == 25)      vh = wxh;       // Wih_hi*(x_hi,x_lo)
                    else if (k == 26)            vh = wx - wxh;  // Wih_lo*x_hi
                    else if (k == 27)            vh = bbh;       // b_hi*1
                    else if (k == 28)            vh = bb - bbh;  // b_lo*1
                }
                fh[jj] = (short)bf16_rne(vh);
                fl[jj] = (short)bf16_rne(vl);
            }
            A[g][s][0] = fh;
            A[g][s][1] = fl;
        }
    }

    // ---- per-lane n-gate x-path constants (exact fp32) ----
    // slot s (0..11) -> unit j = (s&3) + 8*(s>>2) + 4*half  (C-layout rows)
    float wn_s[12], bn_s[12];
#pragma unroll
    for (int s = 0; s < 12; ++s) {
        const int j = (s & 3) + 8 * (s >> 2) + 4 * half;
        wn_s[s] = 2.0f * L2E * W_ih[48 + j];
        bn_s[s] = 2.0f * L2E * b_ih[48 + j];
    }

    const float* xp = x + (size_t)(elem0 + e) * GRU_T;
    float xv = xp[0];

    float h[12];
#pragma unroll
    for (int s = 0; s < 12; ++s) h[s] = 0.0f;

    // packed-bf16 h dwords. In LOW lanes Pk holds units: P0=[0,1] P1=[2,3]
    // P2=[8,9] P3=[10,11] P4=[16,17] P5=[18,19]; in HIGH lanes: P0=[4,5]
    // P1=[6,7] P2=[12,13] P3=[14,15] P4=[20,21] P5=[22,23].
    unsigned P0 = 0, P1 = 0, P2 = 0, P3 = 0, P4 = 0, P5 = 0;

    const f32x16 z16 = {0.f,0.f,0.f,0.f,0.f,0.f,0.f,0.f,
                        0.f,0.f,0.f,0.f,0.f,0.f,0.f,0.f};

#pragma unroll 1
    for (int t = 0; t < GRU_T; ++t) {
        // ---- B fragments entirely in-register via permlane32_swap ----
        const uint2v r02 = __builtin_amdgcn_permlane32_swap(P0, P2, false, false);
        const uint2v r13 = __builtin_amdgcn_permlane32_swap(P1, P3, false, false);
        uint4 b0q;
        b0q.x = r02.x;  // lo:[0,1]   hi:[8,9]
        b0q.y = r13.x;  // lo:[2,3]   hi:[10,11]
        b0q.z = r02.y;  // lo:[4,5]   hi:[12,13]
        b0q.w = r13.y;  // lo:[6,7]   hi:[14,15]

        const uint2v r44 = __builtin_amdgcn_permlane32_swap(P4, P4, false, false);
        const uint2v r55 = __builtin_amdgcn_permlane32_swap(P5, P5, false, false);
        uint4 b1q;
        b1q.x = P4;      // lo:[16,17]
        b1q.y = P5;      // lo:[18,19]
        b1q.z = r44.y;   // lo:[20,21]
        b1q.w = r55.y;   // lo:[22,23]
        if (half) {      // high lanes carry the x/bias K-stream k24..31
            const unsigned xy = cvt_pk_bf16(xv, 1.0f);        // k26=x_hi k27=1.0
            const float    xh = __uint_as_float(xy << 16);    // fp32 of bf16(xv)
            const unsigned xx = cvt_pk_bf16(xv, xv - xh);     // k24=x_hi k25=x_lo
            b1q.x = xx;
            b1q.y = xy;
            b1q.z = 0x00003F80u;                              // k28=1.0 k29=0
            b1q.w = 0u;                                       // k30,k31=0
        }
        const bf16x8 B0 = *(const bf16x8*)&b0q;
        const bf16x8 B1 = *(const bf16x8*)&b1q;
        const float xnext = xp[(t + 1 < GRU_T) ? t + 1 : t];

        f32x16 aR = mfma32(A[0][0][0], B0, z16);
        aR = mfma32(A[0][0][1], B0, aR);
        aR = mfma32(A[0][1][0], B1, aR);
        aR = mfma32(A[0][1][1], B1, aR);
        f32x16 aZ = mfma32(A[1][0][0], B0, z16);
        aZ = mfma32(A[1][0][1], B0, aZ);
        aZ = mfma32(A[1][1][0], B1, aZ);
        aZ = mfma32(A[1][1][1], B1, aZ);
        f32x16 aN = mfma32(A[2][0][0], B0, z16);
        aN = mfma32(A[2][0][1], B0, aN);
        aN = mfma32(A[2][1][0], B1, aN);
        aN = mfma32(A[2][1][1], B1, aN);

        // epilogue: regs 0..11 only (12..15 are pad rows 24..31, skipped)
        // r/z sigmoids share one rcp: rr=dz/(dr*dz), zz=dr/(dr*dz).
#pragma unroll
        for (int G = 0; G < 3; ++G) {
            float hv[4];
#pragma unroll
            for (int q = 0; q < 4; ++q) {
                const int s = G * 4 + q;
                const float er = __builtin_amdgcn_exp2f(-aR[s]);
                const float ez = __builtin_amdgcn_exp2f(-aZ[s]);
                const float dr = 1.0f + er, dz = 1.0f + ez;
                const float qi = __builtin_amdgcn_rcpf(dr * dz);
                const float rr = qi * dz;
                const float zz = qi * dr;
                const float aXv = fmaf(wn_s[s], xv, bn_s[s]);
                const float nn  = tnhf(fmaf(rr, aN[s], aXv));
                const float hn  = fmaf(zz, h[s] - nn, nn);
                h[s] = hn;
                hv[q] = hn;
            }
            const unsigned pa = cvt_pk_bf16(hv[0], hv[1]);
            const unsigned pb = cvt_pk_bf16(hv[2], hv[3]);
            if (G == 0)      { P0 = pa; P1 = pb; }
            else if (G == 1) { P2 = pa; P3 = pb; }
            else             { P4 = pa; P5 = pb; }
        }
        xv = xnext;
    }

    // ---- FC head: h (fp32) -> LDS, lanes 0..31 reduce 24 -> 2 ----
#pragma unroll
    for (int G = 0; G < 3; ++G) {
        float4 f4;
        f4.x = h[G * 4 + 0]; f4.y = h[G * 4 + 1];
        f4.z = h[G * 4 + 2]; f4.w = h[G * 4 + 3];
        *(float4*)(&Flds[e * FS + G * 8 + half * 4]) = f4;
    }
    if (lane < 32) {
        float o0 = fc_b[0], o1 = fc_b[1];
#pragma unroll
        for (int j = 0; j < 24; ++j) {
            const float hv = Flds[lane * FS + j];
            o0 = fmaf(hv, fc_w[j],      o0);
            o1 = fmaf(hv, fc_w[24 + j], o1);
        }
        float2 o; o.x = o0; o.y = o1;
        *(float2*)(out + (size_t)(elem0 + lane) * 2) = o;
    }
}

extern "C" void kernel_launch(void* const* d_in, const int* in_sizes, int n_in,
                              void* d_out, int out_size, void* d_ws, size_t ws_size,
                              hipStream_t stream) {
    const float* x    = (const float*)d_in[0];
    const float* W_ih = (const float*)d_in[1];
    const float* b_ih = (const float*)d_in[2];
    const float* W_hh = (const float*)d_in[3];
    const float* b_hh = (const float*)d_in[4];
    const float* fc_w = (const float*)d_in[5];
    const float* fc_b = (const float*)d_in[6];
    float* out = (float*)d_out;

    const int B = in_sizes[0] / GRU_T;      // 32768
    const int grid = B / 32;                // 1024 blocks x 1 wave
    trend_gru_mfma32<<<grid, 64, 0, stream>>>(x, W_ih, b_ih, W_hh, b_hh,
                                              fc_w, fc_b, out);
}

// Round 2
// 454.519 us; speedup vs baseline: 1.0492x; 1.0459x over previous
//
#include <hip/hip_runtime.h>

// TrendGRU R9: R8 (permlane h-swap, zero LDS in the t-loop) + packed-fp32
// epilogue. Counters said R8 is issue-bound (VALUBusy 64% + MfmaUtil 20% =
// 84% busy at 1 wave/SIMD), so this round halves the non-transcendental
// VALU issue stream: all epilogue adds/muls/fmas run as v_pk_*_f32 on
// slot-pairs (bit-identical per-lane IEEE ops -> absmax must not move).
// Trans count (3 exp2 + 2 rcp per unit) is already the exact-math floor
// and is left untouched. x-path fma (aXv) hoisted out of the MFMA-dependent
// chain and packed. t-loop unrolled x2 for cross-iteration scheduling
// (VGPR headroom is free at 1 wave/SIMD).

#define GRU_T 512
#define FS 28   // FC LDS row stride in floats (16B-aligned float4 rows)

typedef __attribute__((ext_vector_type(8)))  short bf16x8;
typedef __attribute__((ext_vector_type(16))) float f32x16;
typedef __attribute__((ext_vector_type(2)))  float f32x2;
typedef __attribute__((ext_vector_type(2)))  unsigned uint2v;

__device__ __forceinline__ float bf16hi_f(float v) {   // RNE-to-bf16, as float
    unsigned u = __float_as_uint(v);
    u = (u + 0x7FFFu + ((u >> 16) & 1u)) & 0xFFFF0000u;
    return __uint_as_float(u);
}
__device__ __forceinline__ unsigned bf16_rne(float v) {
    unsigned u = __float_as_uint(v);
    return (u + 0x7FFFu + ((u >> 16) & 1u)) >> 16;
}
// packed RNE f32->bf16: dst = [bf16(lo) | bf16(hi)<<16]
__device__ __forceinline__ unsigned cvt_pk_bf16(float lo, float hi) {
    unsigned r;
    asm("v_cvt_pk_bf16_f32 %0, %1, %2" : "=v"(r) : "v"(lo), "v"(hi));
    return r;
}
__device__ __forceinline__ f32x16 mfma32(bf16x8 a, bf16x8 b, f32x16 c) {
    return __builtin_amdgcn_mfma_f32_32x32x16_bf16(a, b, c, 0, 0, 0);
}

__global__ __launch_bounds__(64) void trend_gru_mfma32(
    const float* __restrict__ x,     // (B, T)
    const float* __restrict__ W_ih,  // (72,)
    const float* __restrict__ b_ih,  // (72,)
    const float* __restrict__ W_hh,  // (72, 24) rows r,z,n
    const float* __restrict__ b_hh,  // (72,)
    const float* __restrict__ fc_w,  // (2, 24)
    const float* __restrict__ fc_b,  // (2,)
    float* __restrict__ out)         // (B, 2)
{
    const int lane = threadIdx.x;
    const int e    = lane & 31;          // element (B-col / C-col)
    const int half = lane >> 5;
    const int elem0 = blockIdx.x * 32;

    __shared__ __align__(16) float Flds[32 * FS];

    const float L2E = 1.4426950408889634f;

    // ---- A fragments (weights), built once: A[gate][kstep][hi/lo] ----
    // A layout: row m = lane&31, k = kstep*16 + (lane>>5)*8 + jj.
    bf16x8 A[3][2][2];
#pragma unroll
    for (int g = 0; g < 3; ++g) {
        const float sc = (g == 2) ? 2.0f * L2E : L2E;
        const int m = e;
        const bool valid = m < 24;
        const int R = g * 24 + (valid ? m : 0);
        const float wx = (g < 2 && valid) ? sc * W_ih[R] : 0.0f;
        const float bb = valid ? sc * ((g < 2) ? (b_ih[R] + b_hh[R]) : b_hh[R]) : 0.0f;
        const float wxh = bf16hi_f(wx), bbh = bf16hi_f(bb);
#pragma unroll
        for (int s = 0; s < 2; ++s) {
            bf16x8 fh, fl;
#pragma unroll
            for (int jj = 0; jj < 8; ++jj) {
                const int k = s * 16 + half * 8 + jj;
                float vh = 0.0f, vl = 0.0f;
                if (valid && k < 24) {
                    const float w  = sc * W_hh[R * 24 + k];
                    const float wh = bf16hi_f(w);
                    vh = wh; vl = w - wh;
                } else if (valid) {
                    if (k == 24 || k == 25)      vh = wxh;       // Wih_hi*(x_hi,x_lo)
                    else if (k == 26)            vh = wx - wxh;  // Wih_lo*x_hi
                    else if (k == 27)            vh = bbh;       // b_hi*1
                    else if (k == 28)            vh = bb - bbh;  // b_lo*1
                }
                fh[jj] = (short)bf16_rne(vh);
                fl[jj] = (short)bf16_rne(vl);
            }
            A[g][s][0] = fh;
            A[g][s][1] = fl;
        }
    }

    // ---- per-lane n-gate x-path constants (exact fp32), packed in pairs ----
    // slot s (0..11) -> unit j = (s&3) + 8*(s>>2) + 4*half  (C-layout rows)
    f32x2 wn2[6], bn2[6];
#pragma unroll
    for (int p = 0; p < 6; ++p) {
#pragma unroll
        for (int c = 0; c < 2; ++c) {
            const int s = p * 2 + c;
            const int j = (s & 3) + 8 * (s >> 2) + 4 * half;
            wn2[p][c] = 2.0f * L2E * W_ih[48 + j];
            bn2[p][c] = 2.0f * L2E * b_ih[48 + j];
        }
    }

    const float* xp = x + (size_t)(elem0 + e) * GRU_T;
    float xv = xp[0];

    f32x2 h2[6];
#pragma unroll
    for (int p = 0; p < 6; ++p) { h2[p].x = 0.0f; h2[p].y = 0.0f; }

    // aXv for the CURRENT timestep, precomputed from xv (x-only dependence).
    f32x2 aX2[6];
#pragma unroll
    for (int p = 0; p < 6; ++p) {
        const f32x2 xb = {xv, xv};
        aX2[p] = __builtin_elementwise_fma(wn2[p], xb, bn2[p]);
    }

    // packed-bf16 h dwords. In LOW lanes Pk holds units: P0=[0,1] P1=[2,3]
    // P2=[8,9] P3=[10,11] P4=[16,17] P5=[18,19]; in HIGH lanes: P0=[4,5]
    // P1=[6,7] P2=[12,13] P3=[14,15] P4=[20,21] P5=[22,23].
    unsigned P0 = 0, P1 = 0, P2 = 0, P3 = 0, P4 = 0, P5 = 0;

    const f32x16 z16 = {0.f,0.f,0.f,0.f,0.f,0.f,0.f,0.f,
                        0.f,0.f,0.f,0.f,0.f,0.f,0.f,0.f};

#pragma unroll 2
    for (int t = 0; t < GRU_T; ++t) {
        // ---- B fragments entirely in-register via permlane32_swap ----
        const uint2v r02 = __builtin_amdgcn_permlane32_swap(P0, P2, false, false);
        const uint2v r13 = __builtin_amdgcn_permlane32_swap(P1, P3, false, false);
        uint4 b0q;
        b0q.x = r02.x;  // lo:[0,1]   hi:[8,9]
        b0q.y = r13.x;  // lo:[2,3]   hi:[10,11]
        b0q.z = r02.y;  // lo:[4,5]   hi:[12,13]
        b0q.w = r13.y;  // lo:[6,7]   hi:[14,15]

        const uint2v r44 = __builtin_amdgcn_permlane32_swap(P4, P4, false, false);
        const uint2v r55 = __builtin_amdgcn_permlane32_swap(P5, P5, false, false);
        uint4 b1q;
        b1q.x = P4;      // lo:[16,17]
        b1q.y = P5;      // lo:[18,19]
        b1q.z = r44.y;   // lo:[20,21]
        b1q.w = r55.y;   // lo:[22,23]
        if (half) {      // high lanes carry the x/bias K-stream k24..31
            const unsigned xy = cvt_pk_bf16(xv, 1.0f);        // k26=x_hi k27=1.0
            const float    xh = __uint_as_float(xy << 16);    // fp32 of bf16(xv)
            const unsigned xx = cvt_pk_bf16(xv, xv - xh);     // k24=x_hi k25=x_lo
            b1q.x = xx;
            b1q.y = xy;
            b1q.z = 0x00003F80u;                              // k28=1.0 k29=0
            b1q.w = 0u;                                       // k30,k31=0
        }
        const bf16x8 B0 = *(const bf16x8*)&b0q;
        const bf16x8 B1 = *(const bf16x8*)&b1q;
        const float xnext = xp[(t + 1 < GRU_T) ? t + 1 : t];

        f32x16 aR = mfma32(A[0][0][0], B0, z16);
        aR = mfma32(A[0][0][1], B0, aR);
        aR = mfma32(A[0][1][0], B1, aR);
        aR = mfma32(A[0][1][1], B1, aR);
        f32x16 aZ = mfma32(A[1][0][0], B0, z16);
        aZ = mfma32(A[1][0][1], B0, aZ);
        aZ = mfma32(A[1][1][0], B1, aZ);
        aZ = mfma32(A[1][1][1], B1, aZ);
        f32x16 aN = mfma32(A[2][0][0], B0, z16);
        aN = mfma32(A[2][0][1], B0, aN);
        aN = mfma32(A[2][1][0], B1, aN);
        aN = mfma32(A[2][1][1], B1, aN);

        // ---- epilogue: packed fp32 over slot-pairs, bit-identical ops ----
        // per slot: er=2^-ar ez=2^-az dr=1+er dz=1+ez qi=rcp(dr*dz)
        // rr=qi*dz zz=qi*dr u=fma(rr,an,aX) ev=2^u dv=1+ev rv=rcp(dv)
        // nn=fma(-2,rv,1) hn=fma(zz,h-nn,nn)
#pragma unroll
        for (int G = 0; G < 3; ++G) {
            unsigned pk[2];
#pragma unroll
            for (int p = 0; p < 2; ++p) {
                const int s = G * 4 + p * 2;
                f32x2 er2, ez2, qi2, ev2, rv2;
                er2.x = __builtin_amdgcn_exp2f(-aR[s]);
                er2.y = __builtin_amdgcn_exp2f(-aR[s + 1]);
                ez2.x = __builtin_amdgcn_exp2f(-aZ[s]);
                ez2.y = __builtin_amdgcn_exp2f(-aZ[s + 1]);
                const f32x2 one2 = {1.0f, 1.0f};
                const f32x2 dr2 = er2 + one2;          // v_pk_add_f32
                const f32x2 dz2 = ez2 + one2;
                const f32x2 pp2 = dr2 * dz2;           // v_pk_mul_f32
                qi2.x = __builtin_amdgcn_rcpf(pp2.x);
                qi2.y = __builtin_amdgcn_rcpf(pp2.y);
                const f32x2 rr2 = qi2 * dz2;
                const f32x2 zz2 = qi2 * dr2;
                const f32x2 an2 = {aN[s], aN[s + 1]};
                const f32x2 u2  = __builtin_elementwise_fma(rr2, an2, aX2[G * 2 + p]);
                ev2.x = __builtin_amdgcn_exp2f(u2.x);
                ev2.y = __builtin_amdgcn_exp2f(u2.y);
                const f32x2 dv2 = ev2 + one2;
                rv2.x = __builtin_amdgcn_rcpf(dv2.x);
                rv2.y = __builtin_amdgcn_rcpf(dv2.y);
                const f32x2 m2   = {-2.0f, -2.0f};
                const f32x2 nn2  = __builtin_elementwise_fma(m2, rv2, one2);
                const f32x2 hm2  = h2[G * 2 + p] - nn2;
                const f32x2 hn2  = __builtin_elementwise_fma(zz2, hm2, nn2);
                h2[G * 2 + p] = hn2;
                pk[p] = cvt_pk_bf16(hn2.x, hn2.y);
            }
            if (G == 0)      { P0 = pk[0]; P1 = pk[1]; }
            else if (G == 1) { P2 = pk[0]; P3 = pk[1]; }
            else             { P4 = pk[0]; P5 = pk[1]; }
        }

        xv = xnext;
        // aXv for next timestep (x-only dependence, off the h critical path)
#pragma unroll
        for (int p = 0; p < 6; ++p) {
            const f32x2 xb = {xv, xv};
            aX2[p] = __builtin_elementwise_fma(wn2[p], xb, bn2[p]);
        }
    }

    // ---- FC head: h (fp32) -> LDS, lanes 0..31 reduce 24 -> 2 ----
#pragma unroll
    for (int G = 0; G < 3; ++G) {
        float4 f4;
        f4.x = h2[G * 2 + 0].x; f4.y = h2[G * 2 + 0].y;
        f4.z = h2[G * 2 + 1].x; f4.w = h2[G * 2 + 1].y;
        *(float4*)(&Flds[e * FS + G * 8 + half * 4]) = f4;
    }
    if (lane < 32) {
        float o0 = fc_b[0], o1 = fc_b[1];
#pragma unroll
        for (int j = 0; j < 24; ++j) {
            const float hv = Flds[lane * FS + j];
            o0 = fmaf(hv, fc_w[j],      o0);
            o1 = fmaf(hv, fc_w[24 + j], o1);
        }
        float2 o; o.x = o0; o.y = o1;
        *(float2*)(out + (size_t)(elem0 + lane) * 2) = o;
    }
}

extern "C" void kernel_launch(void* const* d_in, const int* in_sizes, int n_in,
                              void* d_out, int out_size, void* d_ws, size_t ws_size,
                              hipStream_t stream) {
    const float* x    = (const float*)d_in[0];
    const float* W_ih = (const float*)d_in[1];
    const float* b_ih = (const float*)d_in[2];
    const float* W_hh = (const float*)d_in[3];
    const float* b_hh = (const float*)d_in[4];
    const float* fc_w = (const float*)d_in[5];
    const float* fc_b = (const float*)d_in[6];
    float* out = (float*)d_out;

    const int B = in_sizes[0] / GRU_T;      // 32768
    const int grid = B / 32;                // 1024 blocks x 1 wave
    trend_gru_mfma32<<<grid, 64, 0, stream>>>(x, W_ih, b_ih, W_hh, b_hh,
                                              fc_w, fc_b, out);
}

// Round 3
// 454.006 us; speedup vs baseline: 1.0503x; 1.0011x over previous
//
#include <hip/hip_runtime.h>

// TrendGRU R10: R9 + (a) grouped reciprocals (1 rcp per slot-pair for r/z,
// 1 per pair for n: 60 -> 48 trans/timestep; trans at ~16cy dominate VALU)
// and (b) software-pipelined B0/B1 split: B1 of t+1 needs only units 16..23
// (pairs 4,5), so each iteration runs epi(4,5) -> build B1 -> issue 6
// B1-MFMAs(t+1) -> epi(0..3) [~500cy VALU overlapping the B1 chains] ->
// build B0 -> issue 6 B0-MFMAs. This halves the MFMA-drain bubble the R9
// counters exposed (VALU 1142cy + MFMA 410cy + ~400cy neither-busy).
// Cycle model from R9 counters: 12 MFMA x 34cy pipe, 60 trans x 16cy.

#define GRU_T 512
#define FS 28   // FC LDS row stride in floats (16B-aligned float4 rows)

typedef __attribute__((ext_vector_type(8)))  short bf16x8;
typedef __attribute__((ext_vector_type(16))) float f32x16;
typedef __attribute__((ext_vector_type(2)))  float f32x2;
typedef __attribute__((ext_vector_type(2)))  unsigned uint2v;

__device__ __forceinline__ float bf16hi_f(float v) {   // RNE-to-bf16, as float
    unsigned u = __float_as_uint(v);
    u = (u + 0x7FFFu + ((u >> 16) & 1u)) & 0xFFFF0000u;
    return __uint_as_float(u);
}
__device__ __forceinline__ unsigned bf16_rne(float v) {
    unsigned u = __float_as_uint(v);
    return (u + 0x7FFFu + ((u >> 16) & 1u)) >> 16;
}
// packed RNE f32->bf16: dst = [bf16(lo) | bf16(hi)<<16]
__device__ __forceinline__ unsigned cvt_pk_bf16(float lo, float hi) {
    unsigned r;
    asm("v_cvt_pk_bf16_f32 %0, %1, %2" : "=v"(r) : "v"(lo), "v"(hi));
    return r;
}
__device__ __forceinline__ f32x16 mfma32(bf16x8 a, bf16x8 b, f32x16 c) {
    return __builtin_amdgcn_mfma_f32_32x32x16_bf16(a, b, c, 0, 0, 0);
}

// one slot-pair epilogue: r/z sigmoids share one rcp (Q*pp.y, Q*pp.x),
// n-tanh pair shares one rcp likewise. 6 exp2 + 2 rcp per pair.
__device__ __forceinline__ unsigned pair_epi(float ar0, float ar1,
                                             float az0, float az1,
                                             float an0, float an1,
                                             const f32x2 aX, f32x2& h)
{
    const f32x2 one2 = {1.0f, 1.0f};
    f32x2 er2, ez2, ev2;
    er2.x = __builtin_amdgcn_exp2f(-ar0);
    er2.y = __builtin_amdgcn_exp2f(-ar1);
    ez2.x = __builtin_amdgcn_exp2f(-az0);
    ez2.y = __builtin_amdgcn_exp2f(-az1);
    const f32x2 dr2 = er2 + one2;
    const f32x2 dz2 = ez2 + one2;
    const f32x2 pp2 = dr2 * dz2;
    const float  Q  = __builtin_amdgcn_rcpf(pp2.x * pp2.y);
    f32x2 qi2; qi2.x = Q * pp2.y; qi2.y = Q * pp2.x;
    const f32x2 rr2 = qi2 * dz2;
    const f32x2 zz2 = qi2 * dr2;
    const f32x2 an2 = {an0, an1};
    const f32x2 u2  = __builtin_elementwise_fma(rr2, an2, aX);
    ev2.x = __builtin_amdgcn_exp2f(u2.x);
    ev2.y = __builtin_amdgcn_exp2f(u2.y);
    const f32x2 dv2 = ev2 + one2;
    const float  Qn = __builtin_amdgcn_rcpf(dv2.x * dv2.y);
    f32x2 rv2; rv2.x = Qn * dv2.y; rv2.y = Qn * dv2.x;
    const f32x2 m2  = {-2.0f, -2.0f};
    const f32x2 nn2 = __builtin_elementwise_fma(m2, rv2, one2);
    const f32x2 hm2 = h - nn2;
    const f32x2 hn2 = __builtin_elementwise_fma(zz2, hm2, nn2);
    h = hn2;
    return cvt_pk_bf16(hn2.x, hn2.y);
}

__global__ __launch_bounds__(64) void trend_gru_mfma32(
    const float* __restrict__ x,     // (B, T)
    const float* __restrict__ W_ih,  // (72,)
    const float* __restrict__ b_ih,  // (72,)
    const float* __restrict__ W_hh,  // (72, 24) rows r,z,n
    const float* __restrict__ b_hh,  // (72,)
    const float* __restrict__ fc_w,  // (2, 24)
    const float* __restrict__ fc_b,  // (2,)
    float* __restrict__ out)         // (B, 2)
{
    const int lane = threadIdx.x;
    const int e    = lane & 31;          // element (B-col / C-col)
    const int half = lane >> 5;
    const int elem0 = blockIdx.x * 32;

    __shared__ __align__(16) float Flds[32 * FS];

    const float L2E = 1.4426950408889634f;

    // ---- A fragments (weights), built once: A[gate][kstep][hi/lo] ----
    // A layout: row m = lane&31, k = kstep*16 + (lane>>5)*8 + jj.
    bf16x8 A[3][2][2];
#pragma unroll
    for (int g = 0; g < 3; ++g) {
        const float sc = (g == 2) ? 2.0f * L2E : L2E;
        const int m = e;
        const bool valid = m < 24;
        const int R = g * 24 + (valid ? m : 0);
        const float wx = (g < 2 && valid) ? sc * W_ih[R] : 0.0f;
        const float bb = valid ? sc * ((g < 2) ? (b_ih[R] + b_hh[R]) : b_hh[R]) : 0.0f;
        const float wxh = bf16hi_f(wx), bbh = bf16hi_f(bb);
#pragma unroll
        for (int s = 0; s < 2; ++s) {
            bf16x8 fh, fl;
#pragma unroll
            for (int jj = 0; jj < 8; ++jj) {
                const int k = s * 16 + half * 8 + jj;
                float vh = 0.0f, vl = 0.0f;
                if (valid && k < 24) {
                    const float w  = sc * W_hh[R * 24 + k];
                    const float wh = bf16hi_f(w);
                    vh = wh; vl = w - wh;
                } else if (valid) {
                    if (k == 24 || k == 25)      vh = wxh;       // Wih_hi*(x_hi,x_lo)
                    else if (k == 26)            vh = wx - wxh;  // Wih_lo*x_hi
                    else if (k == 27)            vh = bbh;       // b_hi*1
                    else if (k == 28)            vh = bb - bbh;  // b_lo*1
                }
                fh[jj] = (short)bf16_rne(vh);
                fl[jj] = (short)bf16_rne(vl);
            }
            A[g][s][0] = fh;
            A[g][s][1] = fl;
        }
    }

    // ---- per-lane n-gate x-path constants (exact fp32), packed in pairs ----
    // slot s (0..11) -> unit j = (s&3) + 8*(s>>2) + 4*half  (C-layout rows)
    f32x2 wn2[6], bn2[6];
#pragma unroll
    for (int p = 0; p < 6; ++p) {
#pragma unroll
        for (int c = 0; c < 2; ++c) {
            const int s = p * 2 + c;
            const int j = (s & 3) + 8 * (s >> 2) + 4 * half;
            wn2[p][c] = 2.0f * L2E * W_ih[48 + j];
            bn2[p][c] = 2.0f * L2E * b_ih[48 + j];
        }
    }

    const float* xp = x + (size_t)(elem0 + e) * GRU_T;

    f32x2 h2[6];
#pragma unroll
    for (int p = 0; p < 6; ++p) { h2[p].x = 0.0f; h2[p].y = 0.0f; }

    const f32x16 z16 = {0.f,0.f,0.f,0.f,0.f,0.f,0.f,0.f,
                        0.f,0.f,0.f,0.f,0.f,0.f,0.f,0.f};

    // ---- prologue: B(0) from h=0 (P dwords all zero) + x(0) pack ----
    float xv    = xp[0];
    float xnext = xp[1];

    f32x2 aX2[6];
#pragma unroll
    for (int p = 0; p < 6; ++p) {
        const f32x2 xb = {xv, xv};
        aX2[p] = __builtin_elementwise_fma(wn2[p], xb, bn2[p]);
    }

    f32x16 aR, aZ, aN;
    {
        uint4 b1q; b1q.x = 0u; b1q.y = 0u; b1q.z = 0u; b1q.w = 0u;
        if (half) {
            const unsigned xy = cvt_pk_bf16(xv, 1.0f);        // k26=x_hi k27=1.0
            const float    xh = __uint_as_float(xy << 16);
            const unsigned xx = cvt_pk_bf16(xv, xv - xh);     // k24=x_hi k25=x_lo
            b1q.x = xx; b1q.y = xy; b1q.z = 0x00003F80u; b1q.w = 0u;
        }
        const bf16x8 B1 = *(const bf16x8*)&b1q;
        uint4 b0q; b0q.x = 0u; b0q.y = 0u; b0q.z = 0u; b0q.w = 0u;
        const bf16x8 B0 = *(const bf16x8*)&b0q;
        aR = mfma32(A[0][1][0], B1, mfma32(A[0][1][1], B1, z16));
        aZ = mfma32(A[1][1][0], B1, mfma32(A[1][1][1], B1, z16));
        aN = mfma32(A[2][1][0], B1, mfma32(A[2][1][1], B1, z16));
        aR = mfma32(A[0][0][0], B0, mfma32(A[0][0][1], B0, aR));
        aZ = mfma32(A[1][0][0], B0, mfma32(A[1][0][1], B0, aZ));
        aN = mfma32(A[2][0][0], B0, mfma32(A[2][0][1], B0, aN));
    }

    // ---- main loop: epilogue(t) split around MFMA issue for t+1 ----
#pragma unroll 1
    for (int t = 0; t < GRU_T - 1; ++t) {
        // pairs 4,5 (units 16..23) -> P4,P5 -> B1(t+1)
        const unsigned nP4 = pair_epi(aR[8],  aR[9],  aZ[8],  aZ[9],
                                      aN[8],  aN[9],  aX2[4], h2[4]);
        const unsigned nP5 = pair_epi(aR[10], aR[11], aZ[10], aZ[11],
                                      aN[10], aN[11], aX2[5], h2[5]);
        const uint2v r44 = __builtin_amdgcn_permlane32_swap(nP4, nP4, false, false);
        const uint2v r55 = __builtin_amdgcn_permlane32_swap(nP5, nP5, false, false);
        uint4 b1q;
        b1q.x = nP4;     // lo:[16,17]
        b1q.y = nP5;     // lo:[18,19]
        b1q.z = r44.y;   // lo:[20,21]
        b1q.w = r55.y;   // lo:[22,23]
        if (half) {      // high lanes carry the x/bias K-stream k24..31
            const unsigned xy = cvt_pk_bf16(xnext, 1.0f);     // k26=x_hi k27=1.0
            const float    xh = __uint_as_float(xy << 16);
            const unsigned xx = cvt_pk_bf16(xnext, xnext - xh);
            b1q.x = xx; b1q.y = xy; b1q.z = 0x00003F80u; b1q.w = 0u;
        }
        const bf16x8 B1 = *(const bf16x8*)&b1q;

        // issue the 6 B1-MFMAs for t+1 now; pairs 0..3 epilogue overlaps them
        f32x16 nR = mfma32(A[0][1][0], B1, mfma32(A[0][1][1], B1, z16));
        f32x16 nZ = mfma32(A[1][1][0], B1, mfma32(A[1][1][1], B1, z16));
        f32x16 nN = mfma32(A[2][1][0], B1, mfma32(A[2][1][1], B1, z16));

        // pairs 0..3 (units 0..15) -> P0..P3 -> B0(t+1)
        const unsigned nP0 = pair_epi(aR[0], aR[1], aZ[0], aZ[1],
                                      aN[0], aN[1], aX2[0], h2[0]);
        const unsigned nP1 = pair_epi(aR[2], aR[3], aZ[2], aZ[3],
                                      aN[2], aN[3], aX2[1], h2[1]);
        const unsigned nP2 = pair_epi(aR[4], aR[5], aZ[4], aZ[5],
                                      aN[4], aN[5], aX2[2], h2[2]);
        const unsigned nP3 = pair_epi(aR[6], aR[7], aZ[6], aZ[7],
                                      aN[6], aN[7], aX2[3], h2[3]);
        const uint2v r02 = __builtin_amdgcn_permlane32_swap(nP0, nP2, false, false);
        const uint2v r13 = __builtin_amdgcn_permlane32_swap(nP1, nP3, false, false);
        uint4 b0q;
        b0q.x = r02.x;  // lo:[0,1]   hi:[8,9]
        b0q.y = r13.x;  // lo:[2,3]   hi:[10,11]
        b0q.z = r02.y;  // lo:[4,5]   hi:[12,13]
        b0q.w = r13.y;  // lo:[6,7]   hi:[14,15]
        const bf16x8 B0 = *(const bf16x8*)&b0q;

        nR = mfma32(A[0][0][0], B0, mfma32(A[0][0][1], B0, nR));
        nZ = mfma32(A[1][0][0], B0, mfma32(A[1][0][1], B0, nZ));
        nN = mfma32(A[2][0][0], B0, mfma32(A[2][0][1], B0, nN));

        // advance x; aX2 for epilogue(t+1) (x-only dependence)
        const float xcur = xnext;
        xnext = xp[(t + 2 < GRU_T) ? t + 2 : GRU_T - 1];
#pragma unroll
        for (int p = 0; p < 6; ++p) {
            const f32x2 xb = {xcur, xcur};
            aX2[p] = __builtin_elementwise_fma(wn2[p], xb, bn2[p]);
        }
        aR = nR; aZ = nZ; aN = nN;
    }

    // ---- final epilogue (t = GRU_T-1), no MFMA issue ----
    (void)pair_epi(aR[8],  aR[9],  aZ[8],  aZ[9],  aN[8],  aN[9],  aX2[4], h2[4]);
    (void)pair_epi(aR[10], aR[11], aZ[10], aZ[11], aN[10], aN[11], aX2[5], h2[5]);
    (void)pair_epi(aR[0],  aR[1],  aZ[0],  aZ[1],  aN[0],  aN[1],  aX2[0], h2[0]);
    (void)pair_epi(aR[2],  aR[3],  aZ[2],  aZ[3],  aN[2],  aN[3],  aX2[1], h2[1]);
    (void)pair_epi(aR[4],  aR[5],  aZ[4],  aZ[5],  aN[4],  aN[5],  aX2[2], h2[2]);
    (void)pair_epi(aR[6],  aR[7],  aZ[6],  aZ[7],  aN[6],  aN[7],  aX2[3], h2[3]);

    // ---- FC head: h (fp32) -> LDS, lanes 0..31 reduce 24 -> 2 ----
#pragma unroll
    for (int G = 0; G < 3; ++G) {
        float4 f4;
        f4.x = h2[G * 2 + 0].x; f4.y = h2[G * 2 + 0].y;
        f4.z = h2[G * 2 + 1].x; f4.w = h2[G * 2 + 1].y;
        *(float4*)(&Flds[e * FS + G * 8 + half * 4]) = f4;
    }
    __builtin_amdgcn_s_barrier();
    if (lane < 32) {
        float o0 = fc_b[0], o1 = fc_b[1];
#pragma unroll
        for (int j = 0; j < 24; ++j) {
            const float hv = Flds[lane * FS + j];
            o0 = fmaf(hv, fc_w[j],      o0);
            o1 = fmaf(hv, fc_w[24 + j], o1);
        }
        float2 o; o.x = o0; o.y = o1;
        *(float2*)(out + (size_t)(elem0 + lane) * 2) = o;
    }
}

extern "C" void kernel_launch(void* const* d_in, const int* in_sizes, int n_in,
                              void* d_out, int out_size, void* d_ws, size_t ws_size,
                              hipStream_t stream) {
    const float* x    = (const float*)d_in[0];
    const float* W_ih = (const float*)d_in[1];
    const float* b_ih = (const float*)d_in[2];
    const float* W_hh = (const float*)d_in[3];
    const float* b_hh = (const float*)d_in[4];
    const float* fc_w = (const float*)d_in[5];
    const float* fc_b = (const float*)d_in[6];
    float* out = (float*)d_out;

    const int B = in_sizes[0] / GRU_T;      // 32768
    const int grid = B / 32;                // 1024 blocks x 1 wave
    trend_gru_mfma32<<<grid, 64, 0, stream>>>(x, W_ih, b_ih, W_hh, b_hh,
                                              fc_w, fc_b, out);
}